// Round 1
// baseline (5817.190 us; speedup 1.0000x reference)
//
#include <hip/hip_runtime.h>

#define LSEQ 50
#define BATCH 256
#define DIN 256
#define LAT 512
#define HID 1024
#define ROWSTRIDE 257  // D_IN + 1 (dt channel)

typedef __attribute__((ext_vector_type(8))) short s16x8;
typedef __attribute__((ext_vector_type(4))) float f32x4;
using u16 = unsigned short;

__device__ __forceinline__ u16 bfhi(float v) {
  union { float f; unsigned u; } a; a.f = v;
  return (u16)((a.u + 0x7FFFu + ((a.u >> 16) & 1u)) >> 16);
}
__device__ __forceinline__ void split2(float v, u16& h, u16& l) {
  u16 hu = bfhi(v);
  union { unsigned u; float f; } hf; hf.u = ((unsigned)hu) << 16;
  h = hu; l = bfhi(v - hf.f);
}
__device__ __forceinline__ float p2f(u16 h, u16 l) {
  union { unsigned u; float f; } a, b;
  a.u = ((unsigned)h) << 16; b.u = ((unsigned)l) << 16;
  return a.f + b.f;
}
__device__ __forceinline__ float sigmoidf_(float x) { return 1.f / (1.f + __expf(-x)); }
__device__ __forceinline__ f32x4 mfma16(s16x8 a, s16x8 b, f32x4 c) {
  return __builtin_amdgcn_mfma_f32_16x16x32_bf16(a, b, c, 0, 0, 0);
}

// ---------- preprocessing (unchanged) ----------
__global__ __launch_bounds__(256) void tsplit_k(const float* __restrict__ W,
    u16* __restrict__ Thi, u16* __restrict__ Tlo, int K, int N)
{
  __shared__ unsigned Ts[32][33];
  const int bk = blockIdx.x * 32, bn = blockIdx.y * 32;
  const int t = threadIdx.x;
  const int n_l = t & 31, k_l4 = (t >> 5) * 4;
  #pragma unroll
  for (int i = 0; i < 4; i++) {
    float v = W[(size_t)(bk + k_l4 + i) * N + bn + n_l];
    u16 h, l; split2(v, h, l);
    Ts[k_l4 + i][n_l] = ((unsigned)h << 16) | l;
  }
  __syncthreads();
  const int k_l = t & 31, n_l2 = t >> 5;
  #pragma unroll
  for (int i = 0; i < 4; i++) {
    int nn = n_l2 + 8 * i;
    unsigned u = Ts[k_l][nn];
    size_t o = (size_t)(bn + nn) * K + bk + k_l;
    Thi[o] = (u16)(u >> 16);
    Tlo[o] = (u16)(u & 0xFFFFu);
  }
}

__global__ __launch_bounds__(256) void esplit_k(const float* __restrict__ W,
    u16* __restrict__ Phi, u16* __restrict__ Plo)
{
  size_t i4 = ((size_t)blockIdx.x * 256 + threadIdx.x) * 4;
  float4 v = *(const float4*)&W[i4];
  u16 h[4], l[4];
  split2(v.x, h[0], l[0]); split2(v.y, h[1], l[1]);
  split2(v.z, h[2], l[2]); split2(v.w, h[3], l[3]);
  *(ushort4*)&Phi[i4] = make_ushort4(h[0], h[1], h[2], h[3]);
  *(ushort4*)&Plo[i4] = make_ushort4(l[0], l[1], l[2], l[3]);
}

__global__ __launch_bounds__(256) void init_k(u16* __restrict__ c0h, u16* __restrict__ c0l)
{
  size_t i4 = ((size_t)blockIdx.x * 256 + threadIdx.x) * 4;
  *(ushort4*)&c0h[i4] = make_ushort4(0, 0, 0, 0);
  *(ushort4*)&c0l[i4] = make_ushort4(0, 0, 0, 0);
}

// ---------- MLP GEMM: 16x16 tile, 4 waves split-K, LDS-free main loop ----------
// EPI 1: O planes = split(tanh(acc + bias))     grid (N/16=64, 16), KK=512
// EPI 2: y = p2f(O) + (acc+bias)*dt/3; O=split  grid (N/16=32, 16), KK=1024
template<int EPI, int KK>
__global__ __launch_bounds__(256, 4) void mlp_k(
    const u16* __restrict__ Ahi, const u16* __restrict__ Alo,
    const u16* __restrict__ Bhi, const u16* __restrict__ Blo,
    const float* __restrict__ bias,
    u16* __restrict__ Ohi, u16* __restrict__ Olo,
    const float* __restrict__ data, int t)
{
  __shared__ float sP[4][16][17];
  const int tid = threadIdx.x;
  const int n0 = blockIdx.x << 4, m0 = blockIdx.y << 4;
  const int lane = tid & 63, wave = tid >> 6;
  const int lr = lane & 15, lq = lane >> 4;
  constexpr int Kc = KK >> 2;           // per-wave K chunk
  const int k0 = wave * Kc + lq * 8;
  f32x4 acc = {0.f, 0.f, 0.f, 0.f};
  const u16* pah = &Ahi[(size_t)(m0 + lr) * HID + k0];
  const u16* pal = &Alo[(size_t)(m0 + lr) * HID + k0];
  const u16* pbh = &Bhi[(size_t)(n0 + lr) * KK + k0];
  const u16* pbl = &Blo[(size_t)(n0 + lr) * KK + k0];
  constexpr int NITER = Kc >> 5;        // 4 (KK=512) or 8 (KK=1024)
  #pragma unroll 4
  for (int it = 0; it < NITER; ++it) {
    const int ko = it << 5;             // u16 elements
    s16x8 ah = *(const s16x8*)(pah + ko);
    s16x8 al = *(const s16x8*)(pal + ko);
    s16x8 bh = *(const s16x8*)(pbh + ko);
    s16x8 bl = *(const s16x8*)(pbl + ko);
    acc = mfma16(ah, bh, acc);
    acc = mfma16(ah, bl, acc);
    acc = mfma16(al, bh, acc);
  }
  #pragma unroll
  for (int r = 0; r < 4; ++r) sP[wave][lq * 4 + r][lr] = acc[r];
  __syncthreads();
  // one output element per thread
  const int row = tid >> 4, col = tid & 15;
  float v = sP[0][row][col] + sP[1][row][col] + sP[2][row][col] + sP[3][row][col];
  const int grow = m0 + row, gcol = n0 + col;
  v += bias[gcol];
  size_t o = (size_t)grow * HID + gcol;
  if (EPI == 1) {
    float h1 = tanhf(v);
    u16 h, l; split2(h1, h, l);
    Ohi[o] = h; Olo[o] = l;
  } else {
    float dt3 = data[(size_t)(t * BATCH + grow) * ROWSTRIDE + DIN] * (1.f / 3.f);
    float y = p2f(Ohi[o], Olo[o]) + v * dt3;
    u16 h, l; split2(y, h, l);
    Ohi[o] = h; Olo[o] = l;
  }
}

// ---------- fused GRU: 8 waves = {R,Z,Nh,Ni} x {m-half}, LDS-free loops ----------
// grid (1024/16=64 j-tiles, 256/32=8 m-tiles), 512 threads
template<bool PLANES>
__device__ __forceinline__ void loadB(const u16* __restrict__ Bh, const u16* __restrict__ Bl,
                                      const float* __restrict__ Bf,
                                      size_t row, int ld, int k, s16x8& bh, s16x8& bl)
{
  if (PLANES) {
    bh = *(const s16x8*)&Bh[row * (size_t)ld + k];
    bl = *(const s16x8*)&Bl[row * (size_t)ld + k];
  } else {
    const float* p = &Bf[row * (size_t)ld + k];
    float4 f0 = *(const float4*)p;
    float4 f1 = *(const float4*)(p + 4);
    u16 h, l;
    split2(f0.x, h, l); bh[0] = (short)h; bl[0] = (short)l;
    split2(f0.y, h, l); bh[1] = (short)h; bl[1] = (short)l;
    split2(f0.z, h, l); bh[2] = (short)h; bl[2] = (short)l;
    split2(f0.w, h, l); bh[3] = (short)h; bl[3] = (short)l;
    split2(f1.x, h, l); bh[4] = (short)h; bl[4] = (short)l;
    split2(f1.y, h, l); bh[5] = (short)h; bl[5] = (short)l;
    split2(f1.z, h, l); bh[6] = (short)h; bl[6] = (short)l;
    split2(f1.w, h, l); bh[7] = (short)h; bl[7] = (short)l;
  }
}

template<bool PLANES>
__global__ __launch_bounds__(512, 4) void gruf_k(
    const u16* __restrict__ chi, const u16* __restrict__ clo,   // hcat planes [256][1024]
    const float* __restrict__ whh, const u16* __restrict__ whhh, const u16* __restrict__ whhl,
    const float* __restrict__ wih, const u16* __restrict__ wihh, const u16* __restrict__ wihl,
    const float* __restrict__ bih, const float* __restrict__ bhh,
    const float* __restrict__ data, int t,
    u16* __restrict__ nhi, u16* __restrict__ nlo,
    float* __restrict__ out)
{
  __shared__ float sG[8][16][17];
  const int tid = threadIdx.x;
  const int j0 = blockIdx.x << 4, m0 = blockIdx.y << 5;
  const int lane = tid & 63, wave = tid >> 6;
  const int g = wave >> 1, mh = wave & 1;          // gate 0..3, m-half
  const int lr = lane & 15, lq = lane >> 4;
  const int arow = m0 + mh * 16 + lr;
  f32x4 acc = {0.f, 0.f, 0.f, 0.f};

  if (g != 2) {  // gi segment (K=256): gates R(0), Z(1), Ni(3)
    const size_t grow = (size_t)((g == 3 ? 2 : g) * 1024 + j0 + lr);
    const float* xp = &data[(size_t)(t * BATCH + arow) * ROWSTRIDE + lq * 8];
    #pragma unroll 2
    for (int it = 0; it < 8; ++it) {
      const int k = it * 32;
      s16x8 ah, al;
      #pragma unroll
      for (int i = 0; i < 8; ++i) {
        u16 h, l; split2(xp[k + i], h, l);
        ah[i] = (short)h; al[i] = (short)l;
      }
      s16x8 bh, bl;
      loadB<PLANES>(wihh, wihl, wih, grow, 256, k + lq * 8, bh, bl);
      acc = mfma16(ah, bh, acc);
      acc = mfma16(ah, bl, acc);
      acc = mfma16(al, bh, acc);
    }
  }
  if (g != 3) {  // gh segment (K=1024): gates R(0), Z(1), Nh(2)
    const size_t grow = (size_t)(g * 1024 + j0 + lr);
    const u16* pah = &chi[(size_t)arow * HID + lq * 8];
    const u16* pal = &clo[(size_t)arow * HID + lq * 8];
    #pragma unroll 4
    for (int it = 0; it < 32; ++it) {
      const int k = it * 32;
      s16x8 ah = *(const s16x8*)(pah + k);
      s16x8 al = *(const s16x8*)(pal + k);
      s16x8 bh, bl;
      loadB<PLANES>(whhh, whhl, whh, grow, HID, k + lq * 8, bh, bl);
      acc = mfma16(ah, bh, acc);
      acc = mfma16(ah, bl, acc);
      acc = mfma16(al, bh, acc);
    }
  }
  #pragma unroll
  for (int r = 0; r < 4; ++r) sG[wave][lq * 4 + r][lr] = acc[r];
  __syncthreads();

  // epilogue: 512 threads <-> 32 rows x 16 cols
  const int row = tid >> 4, col = tid & 15;
  const int wm = row >> 4, r16 = row & 15;
  const float vR  = sG[0 * 2 + wm][r16][col];
  const float vZ  = sG[1 * 2 + wm][r16][col];
  const float vNh = sG[2 * 2 + wm][r16][col];
  const float vNi = sG[3 * 2 + wm][r16][col];
  const int grow = m0 + row, jg = j0 + col;
  const float rr = sigmoidf_(vR + bih[jg] + bhh[jg]);
  const float zz = sigmoidf_(vZ + bih[1024 + jg] + bhh[1024 + jg]);
  const float nn = tanhf(vNi + bih[2048 + jg] + rr * (vNh + bhh[2048 + jg]));
  const size_t oh = (size_t)grow * HID + jg;
  const float hv = p2f(chi[oh], clo[oh]);
  const float val = (1.f - zz) * nn + zz * hv;
  out[(size_t)LSEQ * BATCH * LAT + oh] = val;        // output 1 (new_h)
  if (jg < LAT) {
    out[((size_t)t * BATCH + grow) * LAT + jg] = val; // output 0
    u16 h, l; split2(val, h, l);
    nhi[oh] = h; nhi[oh + LAT] = h;
    nlo[oh] = l; nlo[oh + LAT] = l;
  }
}

extern "C" void kernel_launch(void* const* d_in, const int* in_sizes, int n_in,
                              void* d_out, int out_size, void* d_ws, size_t ws_size,
                              hipStream_t stream)
{
  const float* data = (const float*)d_in[0];
  const float* w1   = (const float*)d_in[1];
  const float* b1   = (const float*)d_in[2];
  const float* w2   = (const float*)d_in[3];
  const float* b2   = (const float*)d_in[4];
  const float* wih  = (const float*)d_in[5];
  const float* bih  = (const float*)d_in[6];
  const float* whh  = (const float*)d_in[7];
  const float* bhh  = (const float*)d_in[8];
  float* out = (float*)d_out;

  char* w = (char*)d_ws;
  auto alloc = [&](size_t bytes) { char* p = w; w += bytes; return p; };
  u16* w1h = (u16*)alloc((size_t)512 * 1024 * 2);   // [1024 n][512 k] planes
  u16* w1l = (u16*)alloc((size_t)512 * 1024 * 2);
  u16* w2h = (u16*)alloc((size_t)512 * 1024 * 2);   // [512 n][1024 k] planes
  u16* w2l = (u16*)alloc((size_t)512 * 1024 * 2);
  u16* c0h = (u16*)alloc((size_t)BATCH * HID * 2);
  u16* c0l = (u16*)alloc((size_t)BATCH * HID * 2);
  u16* c1h = (u16*)alloc((size_t)BATCH * HID * 2);
  u16* c1l = (u16*)alloc((size_t)BATCH * HID * 2);
  u16* h1h = (u16*)alloc((size_t)BATCH * HID * 2);
  u16* h1l = (u16*)alloc((size_t)BATCH * HID * 2);
  size_t base = (size_t)(w - (char*)d_ws);
  size_t need_opt = base + 2 * ((size_t)3072 * 1024 * 2) + 2 * ((size_t)3072 * 256 * 2);
  bool planes = ws_size >= need_opt;
  u16 *whhh = nullptr, *whhl = nullptr, *wihh = nullptr, *wihl = nullptr;
  if (planes) {
    whhh = (u16*)alloc((size_t)3072 * 1024 * 2);
    whhl = (u16*)alloc((size_t)3072 * 1024 * 2);
    wihh = (u16*)alloc((size_t)3072 * 256 * 2);
    wihl = (u16*)alloc((size_t)3072 * 256 * 2);
  }

  tsplit_k<<<dim3(512 / 32, 1024 / 32), 256, 0, stream>>>(w1, w1h, w1l, 512, 1024);
  tsplit_k<<<dim3(1024 / 32, 512 / 32), 256, 0, stream>>>(w2, w2h, w2l, 1024, 512);
  if (planes) {
    esplit_k<<<dim3((3072 * 1024) / 1024), 256, 0, stream>>>(whh, whhh, whhl);
    esplit_k<<<dim3((3072 * 256) / 1024), 256, 0, stream>>>(wih, wihh, wihl);
  }
  init_k<<<dim3(256), 256, 0, stream>>>(c0h, c0l);

  for (int t = 0; t < LSEQ; ++t) {
    u16* chi = (t & 1) ? c1h : c0h;
    u16* clo = (t & 1) ? c1l : c0l;
    u16* nhi = (t & 1) ? c0h : c1h;
    u16* nlo = (t & 1) ? c0l : c1l;
    for (int s = 0; s < 3; ++s) {
      mlp_k<1, 512><<<dim3(64, 16), 256, 0, stream>>>(chi, clo, w1h, w1l, b1,
                                                      h1h, h1l, data, t);
      mlp_k<2, 1024><<<dim3(32, 16), 256, 0, stream>>>(h1h, h1l, w2h, w2l, b2,
                                                       chi, clo, data, t);
    }
    if (planes)
      gruf_k<true><<<dim3(64, 8), 512, 0, stream>>>(chi, clo,
          whh, whhh, whhl, wih, wihh, wihl, bih, bhh, data, t, nhi, nlo, out);
    else
      gruf_k<false><<<dim3(64, 8), 512, 0, stream>>>(chi, clo,
          whh, whhh, whhl, wih, wihh, wihl, bih, bhh, data, t, nhi, nlo, out);
  }
}